// Round 7
// baseline (650.893 us; speedup 1.0000x reference)
//
#include <hip/hip_runtime.h>
#include <hip/hip_bf16.h>
#include <stdint.h>

#define NN 50000
#define NE 400000
#define CIN 256
#define HID 512
#define COUT 128
#define NG 64
#define SCAN_NB ((NN + 255) / 256)          // 196
#define MT256 ((NN + 255) / 256)            // 196 M-tiles of 256 rows
#define GEMM_NWG (MT256 * 4)                // 784 = 8 * 98 (BN=128 -> 4 n-tiles)

typedef short bf16x8 __attribute__((ext_vector_type(8)));
typedef float f32x4 __attribute__((ext_vector_type(4)));

__device__ inline float bf2f(unsigned short u) {
    union { unsigned int i; float f; } v; v.i = ((unsigned int)u) << 16; return v.f;
}
__device__ inline unsigned short f2bf(float f) {
    union { float f; unsigned int u; } v; v.f = f;
    unsigned int r = v.u + 0x7fffu + ((v.u >> 16) & 1u);
    return (unsigned short)(r >> 16);
}

__device__ inline void async16(const void* g, void* l) {
    __builtin_amdgcn_global_load_lds((const __attribute__((address_space(1))) void*)g,
                                     (__attribute__((address_space(3))) void*)l, 16, 0, 0);
}

// ---------------- small prep kernels ----------------

__global__ void k_f32_to_bf16(const float* __restrict__ in, unsigned short* __restrict__ out, int n4) {
    int i = blockIdx.x * blockDim.x + threadIdx.x;
    if (i < n4) {
        float4 v = ((const float4*)in)[i];
        ushort4 o;
        o.x = f2bf(v.x); o.y = f2bf(v.y); o.z = f2bf(v.z); o.w = f2bf(v.w);
        ((ushort4*)out)[i] = o;
    }
}

// in: [K][N] f32 row-major -> out: [N][K] bf16
__global__ void k_transpose_cvt(const float* __restrict__ in, unsigned short* __restrict__ out, int K, int N) {
    __shared__ float tile[32][33];
    int bx = blockIdx.x * 32, by = blockIdx.y * 32;
    int tx = threadIdx.x & 31, ty = threadIdx.x >> 5; // 256 thr: ty 0..7
    for (int i = 0; i < 32; i += 8)
        tile[ty + i][tx] = in[(size_t)(by + ty + i) * N + bx + tx];
    __syncthreads();
    for (int i = 0; i < 32; i += 8)
        out[(size_t)(bx + ty + i) * K + by + tx] = f2bf(tile[tx][ty + i]);
}

// per-column fused scale/shift for the 5 GEMM epilogues
__global__ void k_affine(const float* __restrict__ enc_b,
                         const float* __restrict__ cb0, const float* __restrict__ bg0, const float* __restrict__ bb0,
                         const float* __restrict__ cb1, const float* __restrict__ bg1, const float* __restrict__ bb1,
                         float* __restrict__ scale, float* __restrict__ shift) {
    int c = threadIdx.x; // 512
    const float inv = 0.9999950000374997f; // 1/sqrt(1+1e-5)
    scale[c] = 1.f; shift[c] = enc_b[c];
    for (int l = 0; l < 2; l++) {
        float s0 = bg0[l * HID + c] * inv;
        scale[(1 + 2 * l) * HID + c] = s0;
        shift[(1 + 2 * l) * HID + c] = cb0[l * HID + c] * s0 + bb0[l * HID + c];
        float s1 = bg1[l * HID + c] * inv;
        scale[(2 + 2 * l) * HID + c] = s1;
        shift[(2 + 2 * l) * HID + c] = cb1[l * HID + c] * s1 + bb1[l * HID + c];
    }
}

// ---------------- CSR build ----------------

__global__ void k_hist(const int* __restrict__ dst, int* __restrict__ indeg, int n) {
    int i = blockIdx.x * blockDim.x + threadIdx.x;
    if (i < n) atomicAdd(&indeg[dst[i]], 1);
}

__global__ void k_scan1(const int* __restrict__ indeg, int* __restrict__ local,
                        int* __restrict__ blocksum, int n) {
    __shared__ int s[256];
    int t = threadIdx.x;
    int i = blockIdx.x * 256 + t;
    int v = (i < n) ? indeg[i] : 0;
    s[t] = v;
    __syncthreads();
    for (int d = 1; d < 256; d <<= 1) {
        int u = (t >= d) ? s[t - d] : 0;
        __syncthreads();
        s[t] += u;
        __syncthreads();
    }
    if (i < n) local[i] = s[t] - v; // exclusive within block
    if (t == 255) blocksum[blockIdx.x] = s[255];
}

__global__ void k_scan2(int* __restrict__ blocksum, int nb) {
    __shared__ int s[256];
    int t = threadIdx.x;
    int v = (t < nb) ? blocksum[t] : 0;
    s[t] = v;
    __syncthreads();
    for (int d = 1; d < 256; d <<= 1) {
        int u = (t >= d) ? s[t - d] : 0;
        __syncthreads();
        s[t] += u;
        __syncthreads();
    }
    if (t < nb) blocksum[t] = s[t] - v; // exclusive block offsets
}

__global__ void k_scan3(const int* __restrict__ local, const int* __restrict__ blocksum,
                        const int* __restrict__ indeg, int* __restrict__ off,
                        int* __restrict__ cursor, int n) {
    int i = blockIdx.x * 256 + threadIdx.x;
    if (i < n) {
        int o = local[i] + blocksum[blockIdx.x];
        off[i] = o;
        cursor[i] = o;
        if (i == n - 1) off[n] = o + indeg[i];
    }
}

__global__ void k_fill(const int* __restrict__ src, const int* __restrict__ dst,
                       int* __restrict__ cursor, int* __restrict__ csr, int n) {
    int i = blockIdx.x * blockDim.x + threadIdx.x;
    if (i < n) {
        int p = atomicAdd(&cursor[dst[i]], 1);
        csr[p] = src[i];
    }
}

// ---------------- aggregation: h = x + sum_{incoming} x[src] ----------------
// one wave per node; 4-way edge unroll for memory-level parallelism

__global__ void k_aggregate(const unsigned short* __restrict__ x, const int* __restrict__ off,
                            const int* __restrict__ csr, unsigned short* __restrict__ h) {
    int wid = (int)((blockIdx.x * blockDim.x + threadIdx.x) >> 6);
    if (wid >= NN) return;
    int lane = threadIdx.x & 63;
    const uint4* xr = (const uint4*)x; // row = 64 uint4
    uint4 v = xr[(size_t)wid * 64 + lane];
    float acc[8];
    {
        unsigned short* p = (unsigned short*)&v;
        for (int i = 0; i < 8; i++) acc[i] = bf2f(p[i]);
    }
    int e0 = off[wid], e1 = off[wid + 1];
    int e = e0;
    for (; e + 3 < e1; e += 4) {
        int u0 = csr[e], u1 = csr[e + 1], u2 = csr[e + 2], u3 = csr[e + 3];
        uint4 v0 = xr[(size_t)u0 * 64 + lane];
        uint4 v1 = xr[(size_t)u1 * 64 + lane];
        uint4 v2 = xr[(size_t)u2 * 64 + lane];
        uint4 v3 = xr[(size_t)u3 * 64 + lane];
        unsigned short* p0 = (unsigned short*)&v0;
        unsigned short* p1 = (unsigned short*)&v1;
        unsigned short* p2 = (unsigned short*)&v2;
        unsigned short* p3 = (unsigned short*)&v3;
#pragma unroll
        for (int i = 0; i < 8; i++)
            acc[i] += (bf2f(p0[i]) + bf2f(p1[i])) + (bf2f(p2[i]) + bf2f(p3[i]));
    }
    for (; e < e1; e++) {
        int u = csr[e];
        uint4 vu = xr[(size_t)u * 64 + lane];
        unsigned short* p = (unsigned short*)&vu;
#pragma unroll
        for (int i = 0; i < 8; i++) acc[i] += bf2f(p[i]);
    }
    uint4 o;
    unsigned short* po = (unsigned short*)&o;
    for (int i = 0; i < 8; i++) po[i] = f2bf(acc[i]);
    ((uint4*)h)[(size_t)wid * 64 + lane] = o;
}

// ---------------- bf16 MFMA GEMM: C[M,512] = A[M,K] * W^T[512,K] ----------------
// R6's verified 2-phase skeleton, scaled to BM=256 x BN=128 with 8 waves:
// 2x MFMA per barrier per SIMD (64 vs 32), staging 96 B/MFMA (was 256),
// half the block count. LDS 2 x 48 KB dbuf. Same transposed-output epilogue
// (mfma(b,a,acc): lr = M-row, lh*4+j = 4 contiguous N-cols, packed 8B stores).

template <int RELU>
__global__ __launch_bounds__(512, 2) void k_gemm(const unsigned short* __restrict__ A,
                                                 const unsigned short* __restrict__ WT,
                                                 const float* __restrict__ scale,
                                                 const float* __restrict__ shift,
                                                 unsigned short* __restrict__ out,
                                                 int M, int K) {
    __shared__ char lds[98304]; // 2 buffers x (A 32 KB + B 16 KB)
    int tid = threadIdx.x, w = tid >> 6, lane = tid & 63;
    int wr = w & 3, wc = w >> 2;          // wave quadrant: rows wr*64.., cols wc*64..
    int lr = lane & 15, lh = lane >> 4;

    // bijective XCD-chunked swizzle, M-major (784 = 8*98): 4 n-tiles of one A-panel adjacent
    int orig = blockIdx.x;
    int wgid = (orig & 7) * (GEMM_NWG / 8) + (orig >> 3);
    int tile_m = (wgid >> 2) * 256;
    int n0 = (wgid & 3) * 128;

    // hoisted per-thread staging addresses: 4 A-chunks + 2 B-chunks per thread
    const unsigned short* gA[4];
    int ldsA[4];
#pragma unroll
    for (int ci = 0; ci < 4; ci++) {
        int c = w * 4 + ci;               // c in [0,32): f=c>>1 (16-row frag), kf=c&1
        int row = tile_m + (c >> 1) * 16 + lr;
        if (row >= M) row = M - 1;
        gA[ci] = A + (size_t)row * K + (c & 1) * 32 + lh * 8;
        ldsA[ci] = c * 1024;
    }
    const unsigned short* gB[2];
    int ldsB[2];
#pragma unroll
    for (int ci = 0; ci < 2; ci++) {
        int c = w * 2 + ci;               // c in [0,16): f=c>>1 (16-col frag), kf=c&1
        gB[ci] = WT + (size_t)(n0 + (c >> 1) * 16 + lr) * K + (c & 1) * 32 + lh * 8;
        ldsB[ci] = 32768 + c * 1024;
    }

    f32x4 acc[4][4];
#pragma unroll
    for (int i = 0; i < 4; i++)
#pragma unroll
        for (int j = 0; j < 4; j++) acc[i][j] = f32x4{0.f, 0.f, 0.f, 0.f};

    int nsteps = K >> 6;
    // prologue: stage step 0 into buffer 0
#pragma unroll
    for (int ci = 0; ci < 4; ci++) async16(gA[ci], lds + ldsA[ci]);
#pragma unroll
    for (int ci = 0; ci < 2; ci++) async16(gB[ci], lds + ldsB[ci]);
    __syncthreads();

    for (int ks = 0; ks < nsteps; ks++) {
        int cur = (ks & 1) ? 49152 : 0;
        if (ks + 1 < nsteps) { // issue next-step loads into the other buffer FIRST
            int nxt = cur ^ 49152;
            int ko = (ks + 1) << 6;
#pragma unroll
            for (int ci = 0; ci < 4; ci++) async16(gA[ci] + ko, lds + nxt + ldsA[ci]);
#pragma unroll
            for (int ci = 0; ci < 2; ci++) async16(gB[ci] + ko, lds + nxt + ldsB[ci]);
        }
#pragma unroll
        for (int kf = 0; kf < 2; kf++) {
            bf16x8 a[4], b[4];
#pragma unroll
            for (int mf = 0; mf < 4; mf++)
                a[mf] = *(const bf16x8*)(lds + cur + (((wr * 4 + mf) * 2) + kf) * 1024 + lane * 16);
#pragma unroll
            for (int nf = 0; nf < 4; nf++)
                b[nf] = *(const bf16x8*)(lds + cur + 32768 + (((wc * 4 + nf) * 2) + kf) * 1024 + lane * 16);
#pragma unroll
            for (int mf = 0; mf < 4; mf++)
#pragma unroll
                for (int nf = 0; nf < 4; nf++)
                    acc[mf][nf] = __builtin_amdgcn_mfma_f32_16x16x32_bf16(b[nf], a[mf], acc[mf][nf], 0, 0, 0);
        }
        __syncthreads(); // one barrier per K-step: drains prefetch + protects buffer swap
    }

    // epilogue (transposed acc): row = M-index from lr, 4 contiguous cols from lh*4
#pragma unroll
    for (int nf = 0; nf < 4; nf++) {
        int col = n0 + wc * 64 + nf * 16 + lh * 4;
        float4 sc = *(const float4*)&scale[col];
        float4 sh = *(const float4*)&shift[col];
#pragma unroll
        for (int mf = 0; mf < 4; mf++) {
            int row = tile_m + wr * 64 + mf * 16 + lr;
            if (row < M) {
                float y0 = acc[mf][nf][0] * sc.x + sh.x;
                float y1 = acc[mf][nf][1] * sc.y + sh.y;
                float y2 = acc[mf][nf][2] * sc.z + sh.z;
                float y3 = acc[mf][nf][3] * sc.w + sh.w;
                if (RELU) {
                    y0 = fmaxf(y0, 0.f); y1 = fmaxf(y1, 0.f);
                    y2 = fmaxf(y2, 0.f); y3 = fmaxf(y3, 0.f);
                }
                ushort4 pk;
                pk.x = f2bf(y0); pk.y = f2bf(y1); pk.z = f2bf(y2); pk.w = f2bf(y3);
                *(ushort4*)(out + (size_t)row * HID + col) = pk;
            }
        }
    }
}

// ---------------- pooling + head ----------------

__global__ void k_bounds(const int* __restrict__ batch, int* __restrict__ bounds) {
    int t = threadIdx.x;
    if (t <= NG) {
        int lo = 0, hi = NN;
        while (lo < hi) { int mid = (lo + hi) >> 1; if (batch[mid] < t) lo = mid + 1; else hi = mid; }
        bounds[t] = lo;
    }
}

__global__ void k_pool(const unsigned short* __restrict__ x, const int* __restrict__ bounds,
                       float* __restrict__ pooled) {
    int g = blockIdx.x, s = blockIdx.y, t = threadIdx.x; // 512 thr
    int b0 = bounds[g], b1 = bounds[g + 1];
    int len = b1 - b0;
    int r0 = b0 + (int)((long long)len * s / 8);
    int r1 = b0 + (int)((long long)len * (s + 1) / 8);
    float acc = 0.f;
    for (int r = r0; r < r1; r++) acc += bf2f(x[(size_t)r * HID + t]);
    if (r1 > r0) atomicAdd(&pooled[g * HID + t], acc);
}

__global__ void k_head1(const float* __restrict__ pooled, const int* __restrict__ bounds,
                        const float* __restrict__ lin_w, const float* __restrict__ lin_b,
                        float* __restrict__ gout) {
    int g = blockIdx.x, t = threadIdx.x; // 512
    __shared__ float row[HID];
    int cnt = bounds[g + 1] - bounds[g];
    float invc = 1.f / fmaxf((float)cnt, 1.f);
    row[t] = pooled[g * HID + t] * invc;
    __syncthreads();
    float acc = lin_b[t];
    for (int k = 0; k < HID; k++) acc += row[k] * lin_w[(size_t)k * HID + t];
    gout[g * HID + t] = 0.5f * acc * (1.f + erff(acc * 0.7071067811865475f));
}

__global__ void k_head2(const float* __restrict__ gbuf, const float* __restrict__ clf_w,
                        const float* __restrict__ clf_b, float* __restrict__ out) {
    int g = blockIdx.x, t = threadIdx.x; // 128
    __shared__ float row[HID];
    for (int k = t; k < HID; k += 128) row[k] = gbuf[g * HID + k];
    __syncthreads();
    float acc = clf_b[t];
    for (int k = 0; k < HID; k++) acc += row[k] * clf_w[(size_t)k * COUT + t];
    out[g * COUT + t] = acc;
}

// ---------------- launch ----------------

extern "C" void kernel_launch(void* const* d_in, const int* in_sizes, int n_in,
                              void* d_out, int out_size, void* d_ws, size_t ws_size,
                              hipStream_t stream) {
    const float* x_f32   = (const float*)d_in[0];
    const int*   ei      = (const int*)d_in[1];
    const int*   batch   = (const int*)d_in[2];
    const float* enc_w   = (const float*)d_in[3];
    const float* enc_b   = (const float*)d_in[4];
    const float* conv_w0 = (const float*)d_in[5];
    const float* conv_b0 = (const float*)d_in[6];
    const float* bn0_g   = (const float*)d_in[7];
    const float* bn0_b   = (const float*)d_in[8];
    const float* conv_w1 = (const float*)d_in[9];
    const float* conv_b1 = (const float*)d_in[10];
    const float* bn1_g   = (const float*)d_in[11];
    const float* bn1_b   = (const float*)d_in[12];
    const float* lin_w   = (const float*)d_in[13];
    const float* lin_b   = (const float*)d_in[14];
    const float* clf_w   = (const float*)d_in[15];
    const float* clf_b   = (const float*)d_in[16];
    const int* srcp = ei;
    const int* dstp = ei + NE;

    char* ws = (char*)d_ws;
    size_t o = 0;
    auto alloc = [&](size_t b) { size_t r = o; o += (b + 255) & ~(size_t)255; return r; };
    unsigned short* buf0 = (unsigned short*)(ws + alloc((size_t)NN * HID * 2));
    unsigned short* buf1 = (unsigned short*)(ws + alloc((size_t)NN * HID * 2));
    unsigned short* buf2 = (unsigned short*)(ws + alloc((size_t)NN * HID * 2));
    unsigned short* xbf = buf1; // alias: encoder input dead before buf1's first real use
    unsigned short* encT = (unsigned short*)(ws + alloc((size_t)HID * CIN * 2));
    unsigned short* c0T  = (unsigned short*)(ws + alloc((size_t)2 * HID * HID * 2));
    unsigned short* c1T  = (unsigned short*)(ws + alloc((size_t)2 * HID * HID * 2));
    float* aff_scale = (float*)(ws + alloc(5 * HID * 4));
    float* aff_shift = (float*)(ws + alloc(5 * HID * 4));
    int* indeg  = (int*)(ws + alloc((size_t)NN * 4));
    int* off    = (int*)(ws + alloc((size_t)(NN + 1) * 4));
    int* cursor = (int*)(ws + alloc((size_t)NN * 4));
    int* csr    = (int*)(ws + alloc((size_t)NE * 4));
    int* scan_local = (int*)(ws + alloc((size_t)NN * 4));
    int* scan_bsum  = (int*)(ws + alloc((size_t)256 * 4));
    int* bounds = (int*)(ws + alloc((size_t)(NG + 1) * 4));
    float* pooled = (float*)(ws + alloc((size_t)NG * HID * 4));
    float* gbuf   = (float*)(ws + alloc((size_t)NG * HID * 4));
    (void)ws_size; (void)n_in; (void)in_sizes; (void)out_size;

    hipMemsetAsync(indeg, 0, (size_t)NN * 4, stream);
    hipMemsetAsync(pooled, 0, (size_t)NG * HID * 4, stream);

    // weight prep
    k_f32_to_bf16<<<(NN * CIN / 4 + 255) / 256, 256, 0, stream>>>(x_f32, xbf, NN * CIN / 4);
    k_transpose_cvt<<<dim3(HID / 32, CIN / 32), 256, 0, stream>>>(enc_w, encT, CIN, HID);
    k_transpose_cvt<<<dim3(16, 16), 256, 0, stream>>>(conv_w0, c0T, HID, HID);
    k_transpose_cvt<<<dim3(16, 16), 256, 0, stream>>>(conv_w0 + HID * HID, c0T + HID * HID, HID, HID);
    k_transpose_cvt<<<dim3(16, 16), 256, 0, stream>>>(conv_w1, c1T, HID, HID);
    k_transpose_cvt<<<dim3(16, 16), 256, 0, stream>>>(conv_w1 + HID * HID, c1T + HID * HID, HID, HID);
    k_affine<<<1, 512, 0, stream>>>(enc_b, conv_b0, bn0_g, bn0_b, conv_b1, bn1_g, bn1_b,
                                    aff_scale, aff_shift);

    // CSR (hierarchical scan)
    k_hist<<<(NE + 255) / 256, 256, 0, stream>>>(dstp, indeg, NE);
    k_scan1<<<SCAN_NB, 256, 0, stream>>>(indeg, scan_local, scan_bsum, NN);
    k_scan2<<<1, 256, 0, stream>>>(scan_bsum, SCAN_NB);
    k_scan3<<<SCAN_NB, 256, 0, stream>>>(scan_local, scan_bsum, indeg, off, cursor, NN);
    k_fill<<<(NE + 255) / 256, 256, 0, stream>>>(srcp, dstp, cursor, csr, NE);
    k_bounds<<<1, 128, 0, stream>>>(batch, bounds);

    // encoder (K=256)
    k_gemm<0><<<GEMM_NWG, 512, 0, stream>>>(xbf, encT, aff_scale, aff_shift, buf0, NN, CIN);

    // GIN layers (K=512)
    for (int l = 0; l < 2; l++) {
        k_aggregate<<<(NN * 64) / 256, 256, 0, stream>>>(buf0, off, csr, buf1);
        k_gemm<1><<<GEMM_NWG, 512, 0, stream>>>(buf1, c0T + (size_t)l * HID * HID,
                                                aff_scale + (1 + 2 * l) * HID, aff_shift + (1 + 2 * l) * HID,
                                                buf2, NN, HID);
        if (l == 0)
            k_gemm<1><<<GEMM_NWG, 512, 0, stream>>>(buf2, c1T + (size_t)l * HID * HID,
                                                    aff_scale + (2 + 2 * l) * HID, aff_shift + (2 + 2 * l) * HID,
                                                    buf0, NN, HID);
        else
            k_gemm<0><<<GEMM_NWG, 512, 0, stream>>>(buf2, c1T + (size_t)l * HID * HID,
                                                    aff_scale + (2 + 2 * l) * HID, aff_shift + (2 + 2 * l) * HID,
                                                    buf0, NN, HID);
    }

    // pool + head
    k_pool<<<dim3(NG, 8), 512, 0, stream>>>(buf0, bounds, pooled);
    k_head1<<<NG, 512, 0, stream>>>(pooled, bounds, lin_w, lin_b, gbuf);
    k_head2<<<NG, 128, 0, stream>>>(gbuf, clf_w, clf_b, (float*)d_out);
}

// Round 8
// 596.811 us; speedup vs baseline: 1.0906x; 1.0906x over previous
//
#include <hip/hip_runtime.h>
#include <hip/hip_bf16.h>
#include <stdint.h>

#define NN 50000
#define NE 400000
#define CIN 256
#define HID 512
#define COUT 128
#define NG 64
#define SCAN_NB ((NN + 255) / 256)          // 196
#define GEMM_NWG (((NN + 127) / 128) * 4)   // 1564 (q=195, r=4 bijective XCD swizzle)

typedef short bf16x8 __attribute__((ext_vector_type(8)));
typedef float f32x4 __attribute__((ext_vector_type(4)));

__device__ inline float bf2f(unsigned short u) {
    union { unsigned int i; float f; } v; v.i = ((unsigned int)u) << 16; return v.f;
}
__device__ inline unsigned short f2bf(float f) {
    union { float f; unsigned int u; } v; v.f = f;
    unsigned int r = v.u + 0x7fffu + ((v.u >> 16) & 1u);
    return (unsigned short)(r >> 16);
}

__device__ inline void async16(const void* g, void* l) {
    __builtin_amdgcn_global_load_lds((const __attribute__((address_space(1))) void*)g,
                                     (__attribute__((address_space(3))) void*)l, 16, 0, 0);
}

// ---------------- small prep kernels ----------------

__global__ void k_f32_to_bf16(const float* __restrict__ in, unsigned short* __restrict__ out, int n4) {
    int i = blockIdx.x * blockDim.x + threadIdx.x;
    if (i < n4) {
        float4 v = ((const float4*)in)[i];
        ushort4 o;
        o.x = f2bf(v.x); o.y = f2bf(v.y); o.z = f2bf(v.z); o.w = f2bf(v.w);
        ((ushort4*)out)[i] = o;
    }
}

// in: [K][N] f32 row-major -> out: [N][K] bf16
__global__ void k_transpose_cvt(const float* __restrict__ in, unsigned short* __restrict__ out, int K, int N) {
    __shared__ float tile[32][33];
    int bx = blockIdx.x * 32, by = blockIdx.y * 32;
    int tx = threadIdx.x & 31, ty = threadIdx.x >> 5; // 256 thr: ty 0..7
    for (int i = 0; i < 32; i += 8)
        tile[ty + i][tx] = in[(size_t)(by + ty + i) * N + bx + tx];
    __syncthreads();
    for (int i = 0; i < 32; i += 8)
        out[(size_t)(bx + ty + i) * K + by + tx] = f2bf(tile[tx][ty + i]);
}

// per-column fused scale/shift for the 5 GEMM epilogues
__global__ void k_affine(const float* __restrict__ enc_b,
                         const float* __restrict__ cb0, const float* __restrict__ bg0, const float* __restrict__ bb0,
                         const float* __restrict__ cb1, const float* __restrict__ bg1, const float* __restrict__ bb1,
                         float* __restrict__ scale, float* __restrict__ shift) {
    int c = threadIdx.x; // 512
    const float inv = 0.9999950000374997f; // 1/sqrt(1+1e-5)
    scale[c] = 1.f; shift[c] = enc_b[c];
    for (int l = 0; l < 2; l++) {
        float s0 = bg0[l * HID + c] * inv;
        scale[(1 + 2 * l) * HID + c] = s0;
        shift[(1 + 2 * l) * HID + c] = cb0[l * HID + c] * s0 + bb0[l * HID + c];
        float s1 = bg1[l * HID + c] * inv;
        scale[(2 + 2 * l) * HID + c] = s1;
        shift[(2 + 2 * l) * HID + c] = cb1[l * HID + c] * s1 + bb1[l * HID + c];
    }
}

// ---------------- CSR build ----------------

__global__ void k_hist(const int* __restrict__ dst, int* __restrict__ indeg, int n) {
    int i = blockIdx.x * blockDim.x + threadIdx.x;
    if (i < n) atomicAdd(&indeg[dst[i]], 1);
}

__global__ void k_scan1(const int* __restrict__ indeg, int* __restrict__ local,
                        int* __restrict__ blocksum, int n) {
    __shared__ int s[256];
    int t = threadIdx.x;
    int i = blockIdx.x * 256 + t;
    int v = (i < n) ? indeg[i] : 0;
    s[t] = v;
    __syncthreads();
    for (int d = 1; d < 256; d <<= 1) {
        int u = (t >= d) ? s[t - d] : 0;
        __syncthreads();
        s[t] += u;
        __syncthreads();
    }
    if (i < n) local[i] = s[t] - v; // exclusive within block
    if (t == 255) blocksum[blockIdx.x] = s[255];
}

__global__ void k_scan2(int* __restrict__ blocksum, int nb) {
    __shared__ int s[256];
    int t = threadIdx.x;
    int v = (t < nb) ? blocksum[t] : 0;
    s[t] = v;
    __syncthreads();
    for (int d = 1; d < 256; d <<= 1) {
        int u = (t >= d) ? s[t - d] : 0;
        __syncthreads();
        s[t] += u;
        __syncthreads();
    }
    if (t < nb) blocksum[t] = s[t] - v; // exclusive block offsets
}

__global__ void k_scan3(const int* __restrict__ local, const int* __restrict__ blocksum,
                        const int* __restrict__ indeg, int* __restrict__ off,
                        int* __restrict__ cursor, int n) {
    int i = blockIdx.x * 256 + threadIdx.x;
    if (i < n) {
        int o = local[i] + blocksum[blockIdx.x];
        off[i] = o;
        cursor[i] = o;
        if (i == n - 1) off[n] = o + indeg[i];
    }
}

__global__ void k_fill(const int* __restrict__ src, const int* __restrict__ dst,
                       int* __restrict__ cursor, int* __restrict__ csr, int n) {
    int i = blockIdx.x * blockDim.x + threadIdx.x;
    if (i < n) {
        int p = atomicAdd(&cursor[dst[i]], 1);
        csr[p] = src[i];
    }
}

// ---------------- aggregation: h = x + sum_{incoming} x[src] ----------------
// one wave per node; 4-way edge unroll for memory-level parallelism

__global__ void k_aggregate(const unsigned short* __restrict__ x, const int* __restrict__ off,
                            const int* __restrict__ csr, unsigned short* __restrict__ h) {
    int wid = (int)((blockIdx.x * blockDim.x + threadIdx.x) >> 6);
    if (wid >= NN) return;
    int lane = threadIdx.x & 63;
    const uint4* xr = (const uint4*)x; // row = 64 uint4
    uint4 v = xr[(size_t)wid * 64 + lane];
    float acc[8];
    {
        unsigned short* p = (unsigned short*)&v;
        for (int i = 0; i < 8; i++) acc[i] = bf2f(p[i]);
    }
    int e0 = off[wid], e1 = off[wid + 1];
    int e = e0;
    for (; e + 3 < e1; e += 4) {
        int u0 = csr[e], u1 = csr[e + 1], u2 = csr[e + 2], u3 = csr[e + 3];
        uint4 v0 = xr[(size_t)u0 * 64 + lane];
        uint4 v1 = xr[(size_t)u1 * 64 + lane];
        uint4 v2 = xr[(size_t)u2 * 64 + lane];
        uint4 v3 = xr[(size_t)u3 * 64 + lane];
        unsigned short* p0 = (unsigned short*)&v0;
        unsigned short* p1 = (unsigned short*)&v1;
        unsigned short* p2 = (unsigned short*)&v2;
        unsigned short* p3 = (unsigned short*)&v3;
#pragma unroll
        for (int i = 0; i < 8; i++)
            acc[i] += (bf2f(p0[i]) + bf2f(p1[i])) + (bf2f(p2[i]) + bf2f(p3[i]));
    }
    for (; e < e1; e++) {
        int u = csr[e];
        uint4 vu = xr[(size_t)u * 64 + lane];
        unsigned short* p = (unsigned short*)&vu;
#pragma unroll
        for (int i = 0; i < 8; i++) acc[i] += bf2f(p[i]);
    }
    uint4 o;
    unsigned short* po = (unsigned short*)&o;
    for (int i = 0; i < 8; i++) po[i] = f2bf(acc[i]);
    ((uint4*)h)[(size_t)wid * 64 + lane] = o;
}

// ---------------- bf16 MFMA GEMM: C[M,512] = A[M,K] * W^T[512,K] ----------------
// R6 geometry (128x128, 4 waves, 64 KB dbuf, M-major XCD swizzle, transposed-output
// epilogue) + T4 COUNTED-VMCNT pipeline: never drain vmcnt to 0 in the main loop.
// Per iter: s_waitcnt vmcnt(8) [wait only cur buffer's 8 loads; next step's stay
// in flight] -> s_barrier -> ds_read+MFMA -> s_barrier -> stage step ks+2 into cur.

template <int RELU, int NSTEPS>
__global__ __launch_bounds__(256) void k_gemm(const unsigned short* __restrict__ A,
                                              const unsigned short* __restrict__ WT,
                                              const float* __restrict__ scale,
                                              const float* __restrict__ shift,
                                              unsigned short* __restrict__ out,
                                              int M, int q, int r) {
    constexpr int K = NSTEPS * 64;
    __shared__ char lds[65536]; // 2 buffers x (A 16 KB + B 16 KB)
    int tid = threadIdx.x, w = tid >> 6, lane = tid & 63;
    int wr = w >> 1, wc = w & 1;
    int lr = lane & 15, lh = lane >> 4;

    // bijective XCD-chunked swizzle (m204), M-major
    int orig = blockIdx.x;
    int xcd = orig & 7, idx = orig >> 3;
    int wgid = (xcd < r ? xcd * (q + 1) : r * (q + 1) + (xcd - r) * q) + idx;
    int tile_m = (wgid >> 2) * 128;
    int n0 = (wgid & 3) * 128;

    // hoisted per-thread staging addresses: 4 A-chunks + 4 B-chunks per thread
    const unsigned short* gA[4];
    const unsigned short* gB[4];
    int ldsoff[4];
#pragma unroll
    for (int ci = 0; ci < 4; ci++) {
        int c = w * 4 + ci;
        int f = c >> 1, kf = c & 1;
        int kcol = kf * 32 + lh * 8;
        int row = tile_m + f * 16 + lr;
        if (row >= M) row = M - 1;
        gA[ci] = A + (size_t)row * K + kcol;
        int nrow = n0 + f * 16 + lr;
        gB[ci] = WT + (size_t)nrow * K + kcol;
        ldsoff[ci] = c * 1024;
    }

    f32x4 acc[4][4];
#pragma unroll
    for (int i = 0; i < 4; i++)
#pragma unroll
        for (int j = 0; j < 4; j++) acc[i][j] = f32x4{0.f, 0.f, 0.f, 0.f};

    // prologue: stage step 0 -> buf0, step 1 -> buf1 (16 loads in flight)
#pragma unroll
    for (int ci = 0; ci < 4; ci++) {
        async16(gA[ci], lds + ldsoff[ci]);
        async16(gB[ci], lds + 16384 + ldsoff[ci]);
    }
#pragma unroll
    for (int ci = 0; ci < 4; ci++) {
        async16(gA[ci] + 64, lds + 32768 + ldsoff[ci]);
        async16(gB[ci] + 64, lds + 32768 + 16384 + ldsoff[ci]);
    }

#pragma unroll
    for (int ks = 0; ks < NSTEPS; ks++) {
        const int cur = (ks & 1) << 15;
        // wait for cur buffer's loads only (oldest 8); keep next step's 8 in flight
        if (ks < NSTEPS - 1) asm volatile("s_waitcnt vmcnt(8)" ::: "memory");
        else                 asm volatile("s_waitcnt vmcnt(0)" ::: "memory");
        __builtin_amdgcn_s_barrier();           // all waves' cur loads landed
        __builtin_amdgcn_sched_barrier(0);
#pragma unroll
        for (int kf = 0; kf < 2; kf++) {
            bf16x8 a[4], b[4];
#pragma unroll
            for (int mf = 0; mf < 4; mf++)
                a[mf] = *(const bf16x8*)(lds + cur + ((wr * 4 + mf) * 2 + kf) * 1024 + lane * 16);
#pragma unroll
            for (int nf = 0; nf < 4; nf++)
                b[nf] = *(const bf16x8*)(lds + cur + 16384 + ((wc * 4 + nf) * 2 + kf) * 1024 + lane * 16);
#pragma unroll
            for (int mf = 0; mf < 4; mf++)
#pragma unroll
                for (int nf = 0; nf < 4; nf++)
                    acc[mf][nf] = __builtin_amdgcn_mfma_f32_16x16x32_bf16(b[nf], a[mf], acc[mf][nf], 0, 0, 0);
        }
        __builtin_amdgcn_sched_barrier(0);
        __builtin_amdgcn_s_barrier();           // all waves done READING cur
        if (ks + 2 < NSTEPS) {                  // stage step ks+2 into the freed buffer
            int ko = (ks + 2) << 6;
#pragma unroll
            for (int ci = 0; ci < 4; ci++) {
                async16(gA[ci] + ko, lds + cur + ldsoff[ci]);
                async16(gB[ci] + ko, lds + cur + 16384 + ldsoff[ci]);
            }
        }
    }

    // epilogue (transposed acc): row = M-index from lr, 4 contiguous cols from lh*4
#pragma unroll
    for (int nf = 0; nf < 4; nf++) {
        int col = n0 + wc * 64 + nf * 16 + lh * 4;
        float4 sc = *(const float4*)&scale[col];
        float4 sh = *(const float4*)&shift[col];
#pragma unroll
        for (int mf = 0; mf < 4; mf++) {
            int row = tile_m + wr * 64 + mf * 16 + lr;
            if (row < M) {
                float y0 = acc[mf][nf][0] * sc.x + sh.x;
                float y1 = acc[mf][nf][1] * sc.y + sh.y;
                float y2 = acc[mf][nf][2] * sc.z + sh.z;
                float y3 = acc[mf][nf][3] * sc.w + sh.w;
                if (RELU) {
                    y0 = fmaxf(y0, 0.f); y1 = fmaxf(y1, 0.f);
                    y2 = fmaxf(y2, 0.f); y3 = fmaxf(y3, 0.f);
                }
                ushort4 pk;
                pk.x = f2bf(y0); pk.y = f2bf(y1); pk.z = f2bf(y2); pk.w = f2bf(y3);
                *(ushort4*)(out + (size_t)row * HID + col) = pk;
            }
        }
    }
}

// ---------------- pooling + head ----------------

__global__ void k_bounds(const int* __restrict__ batch, int* __restrict__ bounds) {
    int t = threadIdx.x;
    if (t <= NG) {
        int lo = 0, hi = NN;
        while (lo < hi) { int mid = (lo + hi) >> 1; if (batch[mid] < t) lo = mid + 1; else hi = mid; }
        bounds[t] = lo;
    }
}

__global__ void k_pool(const unsigned short* __restrict__ x, const int* __restrict__ bounds,
                       float* __restrict__ pooled) {
    int g = blockIdx.x, s = blockIdx.y, t = threadIdx.x; // 512 thr
    int b0 = bounds[g], b1 = bounds[g + 1];
    int len = b1 - b0;
    int r0 = b0 + (int)((long long)len * s / 8);
    int r1 = b0 + (int)((long long)len * (s + 1) / 8);
    float acc = 0.f;
    for (int r = r0; r < r1; r++) acc += bf2f(x[(size_t)r * HID + t]);
    if (r1 > r0) atomicAdd(&pooled[g * HID + t], acc);
}

__global__ void k_head1(const float* __restrict__ pooled, const int* __restrict__ bounds,
                        const float* __restrict__ lin_w, const float* __restrict__ lin_b,
                        float* __restrict__ gout) {
    int g = blockIdx.x, t = threadIdx.x; // 512
    __shared__ float row[HID];
    int cnt = bounds[g + 1] - bounds[g];
    float invc = 1.f / fmaxf((float)cnt, 1.f);
    row[t] = pooled[g * HID + t] * invc;
    __syncthreads();
    float acc = lin_b[t];
    for (int k = 0; k < HID; k++) acc += row[k] * lin_w[(size_t)k * HID + t];
    gout[g * HID + t] = 0.5f * acc * (1.f + erff(acc * 0.7071067811865475f));
}

__global__ void k_head2(const float* __restrict__ gbuf, const float* __restrict__ clf_w,
                        const float* __restrict__ clf_b, float* __restrict__ out) {
    int g = blockIdx.x, t = threadIdx.x; // 128
    __shared__ float row[HID];
    for (int k = t; k < HID; k += 128) row[k] = gbuf[g * HID + k];
    __syncthreads();
    float acc = clf_b[t];
    for (int k = 0; k < HID; k++) acc += row[k] * clf_w[(size_t)k * COUT + t];
    out[g * COUT + t] = acc;
}

// ---------------- launch ----------------

extern "C" void kernel_launch(void* const* d_in, const int* in_sizes, int n_in,
                              void* d_out, int out_size, void* d_ws, size_t ws_size,
                              hipStream_t stream) {
    const float* x_f32   = (const float*)d_in[0];
    const int*   ei      = (const int*)d_in[1];
    const int*   batch   = (const int*)d_in[2];
    const float* enc_w   = (const float*)d_in[3];
    const float* enc_b   = (const float*)d_in[4];
    const float* conv_w0 = (const float*)d_in[5];
    const float* conv_b0 = (const float*)d_in[6];
    const float* bn0_g   = (const float*)d_in[7];
    const float* bn0_b   = (const float*)d_in[8];
    const float* conv_w1 = (const float*)d_in[9];
    const float* conv_b1 = (const float*)d_in[10];
    const float* bn1_g   = (const float*)d_in[11];
    const float* bn1_b   = (const float*)d_in[12];
    const float* lin_w   = (const float*)d_in[13];
    const float* lin_b   = (const float*)d_in[14];
    const float* clf_w   = (const float*)d_in[15];
    const float* clf_b   = (const float*)d_in[16];
    const int* srcp = ei;
    const int* dstp = ei + NE;

    char* ws = (char*)d_ws;
    size_t o = 0;
    auto alloc = [&](size_t b) { size_t r = o; o += (b + 255) & ~(size_t)255; return r; };
    unsigned short* buf0 = (unsigned short*)(ws + alloc((size_t)NN * HID * 2));
    unsigned short* buf1 = (unsigned short*)(ws + alloc((size_t)NN * HID * 2));
    unsigned short* buf2 = (unsigned short*)(ws + alloc((size_t)NN * HID * 2));
    unsigned short* xbf = buf1; // alias: encoder input dead before buf1's first real use
    unsigned short* encT = (unsigned short*)(ws + alloc((size_t)HID * CIN * 2));
    unsigned short* c0T  = (unsigned short*)(ws + alloc((size_t)2 * HID * HID * 2));
    unsigned short* c1T  = (unsigned short*)(ws + alloc((size_t)2 * HID * HID * 2));
    float* aff_scale = (float*)(ws + alloc(5 * HID * 4));
    float* aff_shift = (float*)(ws + alloc(5 * HID * 4));
    int* indeg  = (int*)(ws + alloc((size_t)NN * 4));
    int* off    = (int*)(ws + alloc((size_t)(NN + 1) * 4));
    int* cursor = (int*)(ws + alloc((size_t)NN * 4));
    int* csr    = (int*)(ws + alloc((size_t)NE * 4));
    int* scan_local = (int*)(ws + alloc((size_t)NN * 4));
    int* scan_bsum  = (int*)(ws + alloc((size_t)256 * 4));
    int* bounds = (int*)(ws + alloc((size_t)(NG + 1) * 4));
    float* pooled = (float*)(ws + alloc((size_t)NG * HID * 4));
    float* gbuf   = (float*)(ws + alloc((size_t)NG * HID * 4));
    (void)ws_size; (void)n_in; (void)in_sizes; (void)out_size;

    hipMemsetAsync(indeg, 0, (size_t)NN * 4, stream);
    hipMemsetAsync(pooled, 0, (size_t)NG * HID * 4, stream);

    // weight prep
    k_f32_to_bf16<<<(NN * CIN / 4 + 255) / 256, 256, 0, stream>>>(x_f32, xbf, NN * CIN / 4);
    k_transpose_cvt<<<dim3(HID / 32, CIN / 32), 256, 0, stream>>>(enc_w, encT, CIN, HID);
    k_transpose_cvt<<<dim3(16, 16), 256, 0, stream>>>(conv_w0, c0T, HID, HID);
    k_transpose_cvt<<<dim3(16, 16), 256, 0, stream>>>(conv_w0 + HID * HID, c0T + HID * HID, HID, HID);
    k_transpose_cvt<<<dim3(16, 16), 256, 0, stream>>>(conv_w1, c1T, HID, HID);
    k_transpose_cvt<<<dim3(16, 16), 256, 0, stream>>>(conv_w1 + HID * HID, c1T + HID * HID, HID, HID);
    k_affine<<<1, 512, 0, stream>>>(enc_b, conv_b0, bn0_g, bn0_b, conv_b1, bn1_g, bn1_b,
                                    aff_scale, aff_shift);

    // CSR (hierarchical scan)
    k_hist<<<(NE + 255) / 256, 256, 0, stream>>>(dstp, indeg, NE);
    k_scan1<<<SCAN_NB, 256, 0, stream>>>(indeg, scan_local, scan_bsum, NN);
    k_scan2<<<1, 256, 0, stream>>>(scan_bsum, SCAN_NB);
    k_scan3<<<SCAN_NB, 256, 0, stream>>>(scan_local, scan_bsum, indeg, off, cursor, NN);
    k_fill<<<(NE + 255) / 256, 256, 0, stream>>>(srcp, dstp, cursor, csr, NE);
    k_bounds<<<1, 128, 0, stream>>>(batch, bounds);

    const int gq = GEMM_NWG / 8, gr = GEMM_NWG % 8;

    // encoder (K=256 -> NSTEPS=4)
    k_gemm<0, CIN / 64><<<GEMM_NWG, 256, 0, stream>>>(xbf, encT, aff_scale, aff_shift, buf0, NN, gq, gr);

    // GIN layers (K=512 -> NSTEPS=8)
    for (int l = 0; l < 2; l++) {
        k_aggregate<<<(NN * 64) / 256, 256, 0, stream>>>(buf0, off, csr, buf1);
        k_gemm<1, HID / 64><<<GEMM_NWG, 256, 0, stream>>>(buf1, c0T + (size_t)l * HID * HID,
                                                          aff_scale + (1 + 2 * l) * HID,
                                                          aff_shift + (1 + 2 * l) * HID,
                                                          buf2, NN, gq, gr);
        if (l == 0)
            k_gemm<1, HID / 64><<<GEMM_NWG, 256, 0, stream>>>(buf2, c1T + (size_t)l * HID * HID,
                                                              aff_scale + (2 + 2 * l) * HID,
                                                              aff_shift + (2 + 2 * l) * HID,
                                                              buf0, NN, gq, gr);
        else
            k_gemm<0, HID / 64><<<GEMM_NWG, 256, 0, stream>>>(buf2, c1T + (size_t)l * HID * HID,
                                                              aff_scale + (2 + 2 * l) * HID,
                                                              aff_shift + (2 + 2 * l) * HID,
                                                              buf0, NN, gq, gr);
    }

    // pool + head
    k_pool<<<dim3(NG, 8), 512, 0, stream>>>(buf0, bounds, pooled);
    k_head1<<<NG, 512, 0, stream>>>(pooled, bounds, lin_w, lin_b, gbuf);
    k_head2<<<NG, 128, 0, stream>>>(gbuf, clf_w, clf_b, (float*)d_out);
}

// Round 9
// 582.966 us; speedup vs baseline: 1.1165x; 1.0237x over previous
//
#include <hip/hip_runtime.h>
#include <hip/hip_bf16.h>
#include <stdint.h>

#define NN 50000
#define M_PAD 50048                         // padded rows: 391 tiles of 128
#define NE 400000
#define CIN 256
#define HID 512
#define COUT 128
#define NG 64
#define SCAN_NB ((NN + 255) / 256)          // 196
#define MT128 (M_PAD / 128)                 // 391
#define NTILES (MT128 * 4)                  // 1564; XCD split q=195 r=4
#define GEMM_BLOCKS 512                     // persistent: 2/CU, 64/XCD

typedef short bf16x8 __attribute__((ext_vector_type(8)));
typedef float f32x4 __attribute__((ext_vector_type(4)));
typedef unsigned int u32x2 __attribute__((ext_vector_type(2)));

__device__ inline float bf2f(unsigned short u) {
    union { unsigned int i; float f; } v; v.i = ((unsigned int)u) << 16; return v.f;
}
__device__ inline unsigned short f2bf(float f) {
    union { float f; unsigned int u; } v; v.f = f;
    unsigned int r = v.u + 0x7fffu + ((v.u >> 16) & 1u);
    return (unsigned short)(r >> 16);
}

__device__ inline void async16(const void* g, void* l) {
    __builtin_amdgcn_global_load_lds((const __attribute__((address_space(1))) void*)g,
                                     (__attribute__((address_space(3))) void*)l, 16, 0, 0);
}

// ---------------- small prep kernels ----------------

__global__ void k_f32_to_bf16(const float* __restrict__ in, unsigned short* __restrict__ out, int n4) {
    int i = blockIdx.x * blockDim.x + threadIdx.x;
    if (i < n4) {
        float4 v = ((const float4*)in)[i];
        ushort4 o;
        o.x = f2bf(v.x); o.y = f2bf(v.y); o.z = f2bf(v.z); o.w = f2bf(v.w);
        ((ushort4*)out)[i] = o;
    }
}

// in: [K][N] f32 row-major -> out: [N][K] bf16
__global__ void k_transpose_cvt(const float* __restrict__ in, unsigned short* __restrict__ out, int K, int N) {
    __shared__ float tile[32][33];
    int bx = blockIdx.x * 32, by = blockIdx.y * 32;
    int tx = threadIdx.x & 31, ty = threadIdx.x >> 5; // 256 thr: ty 0..7
    for (int i = 0; i < 32; i += 8)
        tile[ty + i][tx] = in[(size_t)(by + ty + i) * N + bx + tx];
    __syncthreads();
    for (int i = 0; i < 32; i += 8)
        out[(size_t)(bx + ty + i) * K + by + tx] = f2bf(tile[tx][ty + i]);
}

// per-column fused scale/shift for the 5 GEMM epilogues
__global__ void k_affine(const float* __restrict__ enc_b,
                         const float* __restrict__ cb0, const float* __restrict__ bg0, const float* __restrict__ bb0,
                         const float* __restrict__ cb1, const float* __restrict__ bg1, const float* __restrict__ bb1,
                         float* __restrict__ scale, float* __restrict__ shift) {
    int c = threadIdx.x; // 512
    const float inv = 0.9999950000374997f; // 1/sqrt(1+1e-5)
    scale[c] = 1.f; shift[c] = enc_b[c];
    for (int l = 0; l < 2; l++) {
        float s0 = bg0[l * HID + c] * inv;
        scale[(1 + 2 * l) * HID + c] = s0;
        shift[(1 + 2 * l) * HID + c] = cb0[l * HID + c] * s0 + bb0[l * HID + c];
        float s1 = bg1[l * HID + c] * inv;
        scale[(2 + 2 * l) * HID + c] = s1;
        shift[(2 + 2 * l) * HID + c] = cb1[l * HID + c] * s1 + bb1[l * HID + c];
    }
}

// ---------------- CSR build ----------------

__global__ void k_hist(const int* __restrict__ dst, int* __restrict__ indeg, int n) {
    int i = blockIdx.x * blockDim.x + threadIdx.x;
    if (i < n) atomicAdd(&indeg[dst[i]], 1);
}

__global__ void k_scan1(const int* __restrict__ indeg, int* __restrict__ local,
                        int* __restrict__ blocksum, int n) {
    __shared__ int s[256];
    int t = threadIdx.x;
    int i = blockIdx.x * 256 + t;
    int v = (i < n) ? indeg[i] : 0;
    s[t] = v;
    __syncthreads();
    for (int d = 1; d < 256; d <<= 1) {
        int u = (t >= d) ? s[t - d] : 0;
        __syncthreads();
        s[t] += u;
        __syncthreads();
    }
    if (i < n) local[i] = s[t] - v; // exclusive within block
    if (t == 255) blocksum[blockIdx.x] = s[255];
}

__global__ void k_scan2(int* __restrict__ blocksum, int nb) {
    __shared__ int s[256];
    int t = threadIdx.x;
    int v = (t < nb) ? blocksum[t] : 0;
    s[t] = v;
    __syncthreads();
    for (int d = 1; d < 256; d <<= 1) {
        int u = (t >= d) ? s[t - d] : 0;
        __syncthreads();
        s[t] += u;
        __syncthreads();
    }
    if (t < nb) blocksum[t] = s[t] - v; // exclusive block offsets
}

__global__ void k_scan3(const int* __restrict__ local, const int* __restrict__ blocksum,
                        const int* __restrict__ indeg, int* __restrict__ off,
                        int* __restrict__ cursor, int n) {
    int i = blockIdx.x * 256 + threadIdx.x;
    if (i < n) {
        int o = local[i] + blocksum[blockIdx.x];
        off[i] = o;
        cursor[i] = o;
        if (i == n - 1) off[n] = o + indeg[i];
    }
}

__global__ void k_fill(const int* __restrict__ src, const int* __restrict__ dst,
                       int* __restrict__ cursor, int* __restrict__ csr, int n) {
    int i = blockIdx.x * blockDim.x + threadIdx.x;
    if (i < n) {
        int p = atomicAdd(&cursor[dst[i]], 1);
        csr[p] = src[i];
    }
}

// ---------------- aggregation: h = x + sum_{incoming} x[src] ----------------

__global__ void k_aggregate(const unsigned short* __restrict__ x, const int* __restrict__ off,
                            const int* __restrict__ csr, unsigned short* __restrict__ h) {
    int wid = (int)((blockIdx.x * blockDim.x + threadIdx.x) >> 6);
    if (wid >= NN) return;
    int lane = threadIdx.x & 63;
    const uint4* xr = (const uint4*)x; // row = 64 uint4
    uint4 v = xr[(size_t)wid * 64 + lane];
    float acc[8];
    {
        unsigned short* p = (unsigned short*)&v;
        for (int i = 0; i < 8; i++) acc[i] = bf2f(p[i]);
    }
    int e0 = off[wid], e1 = off[wid + 1];
    int e = e0;
    for (; e + 3 < e1; e += 4) {
        int u0 = csr[e], u1 = csr[e + 1], u2 = csr[e + 2], u3 = csr[e + 3];
        uint4 v0 = xr[(size_t)u0 * 64 + lane];
        uint4 v1 = xr[(size_t)u1 * 64 + lane];
        uint4 v2 = xr[(size_t)u2 * 64 + lane];
        uint4 v3 = xr[(size_t)u3 * 64 + lane];
        unsigned short* p0 = (unsigned short*)&v0;
        unsigned short* p1 = (unsigned short*)&v1;
        unsigned short* p2 = (unsigned short*)&v2;
        unsigned short* p3 = (unsigned short*)&v3;
#pragma unroll
        for (int i = 0; i < 8; i++)
            acc[i] += (bf2f(p0[i]) + bf2f(p1[i])) + (bf2f(p2[i]) + bf2f(p3[i]));
    }
    for (; e < e1; e++) {
        int u = csr[e];
        uint4 vu = xr[(size_t)u * 64 + lane];
        unsigned short* p = (unsigned short*)&vu;
#pragma unroll
        for (int i = 0; i < 8; i++) acc[i] += bf2f(p[i]);
    }
    uint4 o;
    unsigned short* po = (unsigned short*)&o;
    for (int i = 0; i < 8; i++) po[i] = f2bf(acc[i]);
    ((uint4*)h)[(size_t)wid * 64 + lane] = o;
}

// ---------------- bf16 MFMA GEMM: C[M_PAD,512] = A[M_PAD,K] * W^T[512,K] ----------------
// PERSISTENT blocks (512 = 2/CU) each own 3-4 tiles; counted-vmcnt pipeline runs
// continuously ACROSS tiles (stage next tile's steps 0/1 during this tile's last 2
// steps; epilogue stores retire under next tile's compute). Static vmcnt counts:
// boundary ks<2 -> vmcnt(24) [8 loads + exactly-16 asm stores after target],
// steady vmcnt(8), final vmcnt(0). M padded to 50048 -> no store guards.
// scale/shift cached in LDS so epilogue issues no VMEM loads.

template <int RELU, int NSTEPS>
__global__ __launch_bounds__(256, 2) void k_gemm(const unsigned short* __restrict__ A,
                                                 const unsigned short* __restrict__ WT,
                                                 const float* __restrict__ scale,
                                                 const float* __restrict__ shift,
                                                 unsigned short* __restrict__ out) {
    constexpr int K = NSTEPS * 64;
    __shared__ char lds[69632]; // [0,64K) dbuf (2 x (A 16K + B 16K)), [64K,66K) scale, [66K,68K) shift
    const int tid = threadIdx.x, w = tid >> 6, lane = tid & 63;
    const int wr = w >> 1, wc = w & 1;
    const int lr = lane & 15, lh = lane >> 4;

    // scale/shift -> LDS once; fully drained before the pipeline starts
    {
        float2 s2 = *(const float2*)(scale + tid * 2);
        float2 h2 = *(const float2*)(shift + tid * 2);
        *(float2*)(lds + 65536 + tid * 8) = s2;
        *(float2*)(lds + 67584 + tid * 8) = h2;
    }
    __syncthreads();

    // persistent tile assignment: XCD-chunked (q=195,r=4), slot-strided
    const int b = blockIdx.x;
    const int xcd = b & 7, slot = b >> 3;
    const int xs = (xcd < 4) ? xcd * 196 : 784 + (xcd - 4) * 195;
    const int xcnt = (xcd < 4) ? 196 : 195;
    const int ntiles = (xcnt - slot + 63) >> 6; // 3 or 4
    int t = xs + slot;

    // tile-independent per-thread chunk offsets
    int ldsoff[4], roff[4];
#pragma unroll
    for (int ci = 0; ci < 4; ci++) {
        int cc = w * 4 + ci;                 // chunk id 0..15
        ldsoff[ci] = cc * 1024;
        roff[ci] = ((cc >> 1) * 16 + lr) * K + (cc & 1) * 32 + lh * 8;
    }

    const unsigned short* gA[4];
    const unsigned short* gB[4];
    {
        int tile_m = (t >> 2) * 128, n0 = (t & 3) * 128;
#pragma unroll
        for (int ci = 0; ci < 4; ci++) {
            gA[ci] = A + (size_t)tile_m * K + roff[ci];
            gB[ci] = WT + (size_t)n0 * K + roff[ci];
        }
    }

    // prologue: stage steps 0,1 of first tile
#pragma unroll
    for (int ci = 0; ci < 4; ci++) { async16(gA[ci], lds + ldsoff[ci]); async16(gB[ci], lds + 16384 + ldsoff[ci]); }
#pragma unroll
    for (int ci = 0; ci < 4; ci++) { async16(gA[ci] + 64, lds + 32768 + ldsoff[ci]); async16(gB[ci] + 64, lds + 32768 + 16384 + ldsoff[ci]); }

    for (int i = 0; i < ntiles; i++) {
        const bool last = (i == ntiles - 1);
        // next-tile pointers (computed branchlessly; only used when !last)
        const unsigned short* nA[4];
        const unsigned short* nB[4];
        {
            int tn = last ? t : t + 64;
            int tile_m = (tn >> 2) * 128, n0 = (tn & 3) * 128;
#pragma unroll
            for (int ci = 0; ci < 4; ci++) {
                nA[ci] = A + (size_t)tile_m * K + roff[ci];
                nB[ci] = WT + (size_t)n0 * K + roff[ci];
            }
        }

        f32x4 acc[4][4];
#pragma unroll
        for (int x = 0; x < 4; x++)
#pragma unroll
            for (int y = 0; y < 4; y++) acc[x][y] = f32x4{0.f, 0.f, 0.f, 0.f};

#pragma unroll
        for (int ks = 0; ks < NSTEPS; ks++) {
            const int cur = (ks & 1) << 15;
            if (i > 0 && ks < 2)                 asm volatile("s_waitcnt vmcnt(24)" ::: "memory");
            else if (last && ks == NSTEPS - 1)   asm volatile("s_waitcnt vmcnt(0)" ::: "memory");
            else                                 asm volatile("s_waitcnt vmcnt(8)" ::: "memory");
            __builtin_amdgcn_s_barrier();
            __builtin_amdgcn_sched_barrier(0);
#pragma unroll
            for (int kf = 0; kf < 2; kf++) {
                bf16x8 a[4], bb[4];
#pragma unroll
                for (int mf = 0; mf < 4; mf++)
                    a[mf] = *(const bf16x8*)(lds + cur + ((wr * 4 + mf) * 2 + kf) * 1024 + lane * 16);
#pragma unroll
                for (int nf = 0; nf < 4; nf++)
                    bb[nf] = *(const bf16x8*)(lds + cur + 16384 + ((wc * 4 + nf) * 2 + kf) * 1024 + lane * 16);
#pragma unroll
                for (int mf = 0; mf < 4; mf++)
#pragma unroll
                    for (int nf = 0; nf < 4; nf++)
                        acc[mf][nf] = __builtin_amdgcn_mfma_f32_16x16x32_bf16(bb[nf], a[mf], acc[mf][nf], 0, 0, 0);
            }
            __builtin_amdgcn_sched_barrier(0);
            __builtin_amdgcn_s_barrier();
            if (ks + 2 < NSTEPS) {               // stage this tile's step ks+2
                int ko = (ks + 2) << 6;
#pragma unroll
                for (int ci = 0; ci < 4; ci++) {
                    async16(gA[ci] + ko, lds + cur + ldsoff[ci]);
                    async16(gB[ci] + ko, lds + cur + 16384 + ldsoff[ci]);
                }
            } else if (!last) {                  // stage NEXT tile's step ks+2-NSTEPS (0 or 1)
                int ko = (ks + 2 - NSTEPS) << 6;
#pragma unroll
                for (int ci = 0; ci < 4; ci++) {
                    async16(nA[ci] + ko, lds + cur + ldsoff[ci]);
                    async16(nB[ci] + ko, lds + cur + 16384 + ldsoff[ci]);
                }
            }
        }

        // epilogue: exactly 16 asm stores per thread (count pinned for vmcnt math);
        // scale/shift from LDS (no VMEM loads). Transposed acc: lr = M-row,
        // lh*4..+3 = 4 contiguous N-cols.
        {
            int tile_m = (t >> 2) * 128, n0 = (t & 3) * 128;
#pragma unroll
            for (int nf = 0; nf < 4; nf++) {
                int col = n0 + wc * 64 + nf * 16 + lh * 4;
                f32x4 sc = *(const f32x4*)(lds + 65536 + ((wc * 64 + nf * 16 + lh * 4) << 2) + (n0 << 2));
                f32x4 sh = *(const f32x4*)(lds + 67584 + ((wc * 64 + nf * 16 + lh * 4) << 2) + (n0 << 2));
#pragma unroll
                for (int mf = 0; mf < 4; mf++) {
                    int row = tile_m + wr * 64 + mf * 16 + lr;
                    float y0 = acc[mf][nf][0] * sc[0] + sh[0];
                    float y1 = acc[mf][nf][1] * sc[1] + sh[1];
                    float y2 = acc[mf][nf][2] * sc[2] + sh[2];
                    float y3 = acc[mf][nf][3] * sc[3] + sh[3];
                    if (RELU) {
                        y0 = fmaxf(y0, 0.f); y1 = fmaxf(y1, 0.f);
                        y2 = fmaxf(y2, 0.f); y3 = fmaxf(y3, 0.f);
                    }
                    u32x2 pd;
                    pd[0] = (unsigned)f2bf(y0) | ((unsigned)f2bf(y1) << 16);
                    pd[1] = (unsigned)f2bf(y2) | ((unsigned)f2bf(y3) << 16);
                    unsigned long long ap = (unsigned long long)(out + (size_t)row * HID + col);
                    asm volatile("global_store_dwordx2 %0, %1, off" :: "v"(ap), "v"(pd) : "memory");
                }
            }
        }

        if (!last) {
#pragma unroll
            for (int ci = 0; ci < 4; ci++) { gA[ci] = nA[ci]; gB[ci] = nB[ci]; }
            t += 64;
        }
    }
}

// ---------------- pooling + head ----------------

__global__ void k_bounds(const int* __restrict__ batch, int* __restrict__ bounds) {
    int t = threadIdx.x;
    if (t <= NG) {
        int lo = 0, hi = NN;
        while (lo < hi) { int mid = (lo + hi) >> 1; if (batch[mid] < t) lo = mid + 1; else hi = mid; }
        bounds[t] = lo;
    }
}

__global__ void k_pool(const unsigned short* __restrict__ x, const int* __restrict__ bounds,
                       float* __restrict__ pooled) {
    int g = blockIdx.x, s = blockIdx.y, t = threadIdx.x; // 512 thr
    int b0 = bounds[g], b1 = bounds[g + 1];
    int len = b1 - b0;
    int r0 = b0 + (int)((long long)len * s / 8);
    int r1 = b0 + (int)((long long)len * (s + 1) / 8);
    float acc = 0.f;
    for (int r = r0; r < r1; r++) acc += bf2f(x[(size_t)r * HID + t]);
    if (r1 > r0) atomicAdd(&pooled[g * HID + t], acc);
}

__global__ void k_head1(const float* __restrict__ pooled, const int* __restrict__ bounds,
                        const float* __restrict__ lin_w, const float* __restrict__ lin_b,
                        float* __restrict__ gout) {
    int g = blockIdx.x, t = threadIdx.x; // 512
    __shared__ float row[HID];
    int cnt = bounds[g + 1] - bounds[g];
    float invc = 1.f / fmaxf((float)cnt, 1.f);
    row[t] = pooled[g * HID + t] * invc;
    __syncthreads();
    float acc = lin_b[t];
    for (int k = 0; k < HID; k++) acc += row[k] * lin_w[(size_t)k * HID + t];
    gout[g * HID + t] = 0.5f * acc * (1.f + erff(acc * 0.7071067811865475f));
}

__global__ void k_head2(const float* __restrict__ gbuf, const float* __restrict__ clf_w,
                        const float* __restrict__ clf_b, float* __restrict__ out) {
    int g = blockIdx.x, t = threadIdx.x; // 128
    __shared__ float row[HID];
    for (int k = t; k < HID; k += 128) row[k] = gbuf[g * HID + k];
    __syncthreads();
    float acc = clf_b[t];
    for (int k = 0; k < HID; k++) acc += row[k] * clf_w[(size_t)k * COUT + t];
    out[g * COUT + t] = acc;
}

// ---------------- launch ----------------

extern "C" void kernel_launch(void* const* d_in, const int* in_sizes, int n_in,
                              void* d_out, int out_size, void* d_ws, size_t ws_size,
                              hipStream_t stream) {
    const float* x_f32   = (const float*)d_in[0];
    const int*   ei      = (const int*)d_in[1];
    const int*   batch   = (const int*)d_in[2];
    const float* enc_w   = (const float*)d_in[3];
    const float* enc_b   = (const float*)d_in[4];
    const float* conv_w0 = (const float*)d_in[5];
    const float* conv_b0 = (const float*)d_in[6];
    const float* bn0_g   = (const float*)d_in[7];
    const float* bn0_b   = (const float*)d_in[8];
    const float* conv_w1 = (const float*)d_in[9];
    const float* conv_b1 = (const float*)d_in[10];
    const float* bn1_g   = (const float*)d_in[11];
    const float* bn1_b   = (const float*)d_in[12];
    const float* lin_w   = (const float*)d_in[13];
    const float* lin_b   = (const float*)d_in[14];
    const float* clf_w   = (const float*)d_in[15];
    const float* clf_b   = (const float*)d_in[16];
    const int* srcp = ei;
    const int* dstp = ei + NE;

    char* ws = (char*)d_ws;
    size_t o = 0;
    auto alloc = [&](size_t b) { size_t r = o; o += (b + 255) & ~(size_t)255; return r; };
    // activation buffers padded to M_PAD rows (garbage rows are finite & never read downstream)
    unsigned short* buf0 = (unsigned short*)(ws + alloc((size_t)M_PAD * HID * 2));
    unsigned short* buf1 = (unsigned short*)(ws + alloc((size_t)M_PAD * HID * 2));
    unsigned short* buf2 = (unsigned short*)(ws + alloc((size_t)M_PAD * HID * 2));
    unsigned short* xbf = buf1; // alias: encoder input dead before buf1's first real use
    unsigned short* encT = (unsigned short*)(ws + alloc((size_t)HID * CIN * 2));
    unsigned short* c0T  = (unsigned short*)(ws + alloc((size_t)2 * HID * HID * 2));
    unsigned short* c1T  = (unsigned short*)(ws + alloc((size_t)2 * HID * HID * 2));
    float* aff_scale = (float*)(ws + alloc(5 * HID * 4));
    float* aff_shift = (float*)(ws + alloc(5 * HID * 4));
    int* indeg  = (int*)(ws + alloc((size_t)NN * 4));
    int* off    = (int*)(ws + alloc((size_t)(NN + 1) * 4));
    int* cursor = (int*)(ws + alloc((size_t)NN * 4));
    int* csr    = (int*)(ws + alloc((size_t)NE * 4));
    int* scan_local = (int*)(ws + alloc((size_t)NN * 4));
    int* scan_bsum  = (int*)(ws + alloc((size_t)256 * 4));
    int* bounds = (int*)(ws + alloc((size_t)(NG + 1) * 4));
    float* pooled = (float*)(ws + alloc((size_t)NG * HID * 4));
    float* gbuf   = (float*)(ws + alloc((size_t)NG * HID * 4));
    (void)ws_size; (void)n_in; (void)in_sizes; (void)out_size;

    hipMemsetAsync(indeg, 0, (size_t)NN * 4, stream);
    hipMemsetAsync(pooled, 0, (size_t)NG * HID * 4, stream);

    // weight prep
    k_f32_to_bf16<<<(NN * CIN / 4 + 255) / 256, 256, 0, stream>>>(x_f32, xbf, NN * CIN / 4);
    k_transpose_cvt<<<dim3(HID / 32, CIN / 32), 256, 0, stream>>>(enc_w, encT, CIN, HID);
    k_transpose_cvt<<<dim3(16, 16), 256, 0, stream>>>(conv_w0, c0T, HID, HID);
    k_transpose_cvt<<<dim3(16, 16), 256, 0, stream>>>(conv_w0 + HID * HID, c0T + HID * HID, HID, HID);
    k_transpose_cvt<<<dim3(16, 16), 256, 0, stream>>>(conv_w1, c1T, HID, HID);
    k_transpose_cvt<<<dim3(16, 16), 256, 0, stream>>>(conv_w1 + HID * HID, c1T + HID * HID, HID, HID);
    k_affine<<<1, 512, 0, stream>>>(enc_b, conv_b0, bn0_g, bn0_b, conv_b1, bn1_g, bn1_b,
                                    aff_scale, aff_shift);

    // CSR (hierarchical scan)
    k_hist<<<(NE + 255) / 256, 256, 0, stream>>>(dstp, indeg, NE);
    k_scan1<<<SCAN_NB, 256, 0, stream>>>(indeg, scan_local, scan_bsum, NN);
    k_scan2<<<1, 256, 0, stream>>>(scan_bsum, SCAN_NB);
    k_scan3<<<SCAN_NB, 256, 0, stream>>>(scan_local, scan_bsum, indeg, off, cursor, NN);
    k_fill<<<(NE + 255) / 256, 256, 0, stream>>>(srcp, dstp, cursor, csr, NE);
    k_bounds<<<1, 128, 0, stream>>>(batch, bounds);

    // encoder (K=256 -> NSTEPS=4)
    k_gemm<0, CIN / 64><<<GEMM_BLOCKS, 256, 0, stream>>>(xbf, encT, aff_scale, aff_shift, buf0);

    // GIN layers (K=512 -> NSTEPS=8)
    for (int l = 0; l < 2; l++) {
        k_aggregate<<<(NN * 64) / 256, 256, 0, stream>>>(buf0, off, csr, buf1);
        k_gemm<1, HID / 64><<<GEMM_BLOCKS, 256, 0, stream>>>(buf1, c0T + (size_t)l * HID * HID,
                                                             aff_scale + (1 + 2 * l) * HID,
                                                             aff_shift + (1 + 2 * l) * HID,
                                                             buf2);
        if (l == 0)
            k_gemm<1, HID / 64><<<GEMM_BLOCKS, 256, 0, stream>>>(buf2, c1T + (size_t)l * HID * HID,
                                                                 aff_scale + (2 + 2 * l) * HID,
                                                                 aff_shift + (2 + 2 * l) * HID,
                                                                 buf0);
        else
            k_gemm<0, HID / 64><<<GEMM_BLOCKS, 256, 0, stream>>>(buf2, c1T + (size_t)l * HID * HID,
                                                                 aff_scale + (2 + 2 * l) * HID,
                                                                 aff_shift + (2 + 2 * l) * HID,
                                                                 buf0);
    }

    // pool + head
    k_pool<<<dim3(NG, 8), 512, 0, stream>>>(buf0, bounds, pooled);
    k_head1<<<NG, 512, 0, stream>>>(pooled, bounds, lin_w, lin_b, gbuf);
    k_head2<<<NG, 128, 0, stream>>>(gbuf, clf_w, clf_b, (float*)d_out);
}

// Round 10
// 478.873 us; speedup vs baseline: 1.3592x; 1.2174x over previous
//
#include <hip/hip_runtime.h>
#include <hip/hip_bf16.h>
#include <stdint.h>

#define NN 50000
#define M_PAD 50048                         // padded rows: 391 tiles of 128
#define NE 400000
#define CIN 256
#define KF 320                              // fused layer-0 K: 256 feats + 1 deg col + 63 zeros
#define HID 512
#define COUT 128
#define NG 64
#define SCAN_NB ((NN + 255) / 256)          // 196
#define MT128 (M_PAD / 128)                 // 391
#define GEMM_BLOCKS 512                     // persistent: 2/CU, 64/XCD

typedef short bf16x8 __attribute__((ext_vector_type(8)));
typedef float f32x4 __attribute__((ext_vector_type(4)));
typedef unsigned int u32x2 __attribute__((ext_vector_type(2)));

__device__ inline float bf2f(unsigned short u) {
    union { unsigned int i; float f; } v; v.i = ((unsigned int)u) << 16; return v.f;
}
__device__ inline unsigned short f2bf(float f) {
    union { float f; unsigned int u; } v; v.f = f;
    unsigned int r = v.u + 0x7fffu + ((v.u >> 16) & 1u);
    return (unsigned short)(r >> 16);
}

__device__ inline void async16(const void* g, void* l) {
    __builtin_amdgcn_global_load_lds((const __attribute__((address_space(1))) void*)g,
                                     (__attribute__((address_space(3))) void*)l, 16, 0, 0);
}

// ---------------- small prep kernels ----------------

__global__ void k_f32_to_bf16(const float* __restrict__ in, unsigned short* __restrict__ out, int n4) {
    int i = blockIdx.x * blockDim.x + threadIdx.x;
    if (i < n4) {
        float4 v = ((const float4*)in)[i];
        ushort4 o;
        o.x = f2bf(v.x); o.y = f2bf(v.y); o.z = f2bf(v.z); o.w = f2bf(v.w);
        ((ushort4*)out)[i] = o;
    }
}

// in: [K][N] f32 row-major -> out: [N][K] bf16
__global__ void k_transpose_cvt(const float* __restrict__ in, unsigned short* __restrict__ out, int K, int N) {
    __shared__ float tile[32][33];
    int bx = blockIdx.x * 32, by = blockIdx.y * 32;
    int tx = threadIdx.x & 31, ty = threadIdx.x >> 5; // 256 thr: ty 0..7
    for (int i = 0; i < 32; i += 8)
        tile[ty + i][tx] = in[(size_t)(by + ty + i) * N + bx + tx];
    __syncthreads();
    for (int i = 0; i < 32; i += 8)
        out[(size_t)(bx + ty + i) * K + by + tx] = f2bf(tile[tx][ty + i]);
}

// fused layer-0 weight: WfT[n][k] = (enc_w @ W0)[k][n] for k<256; row 256 = enc_b@W0; rest 0
__global__ void k_fuse_w0(const float* __restrict__ enc_w, const float* __restrict__ enc_b,
                          const float* __restrict__ W0, unsigned short* __restrict__ WfT) {
    int n = blockIdx.x;                 // 0..511
    __shared__ float col[HID];
    for (int j = threadIdx.x; j < HID; j += 256) col[j] = W0[(size_t)j * HID + n];
    __syncthreads();
    int k = threadIdx.x;                // 0..255
    float acc = 0.f;
    for (int j = 0; j < HID; j++) acc += enc_w[(size_t)k * HID + j] * col[j];
    WfT[(size_t)n * KF + k] = f2bf(acc);
    if (k == 0) {
        float v = 0.f;
        for (int j = 0; j < HID; j++) v += enc_b[j] * col[j];
        WfT[(size_t)n * KF + 256] = f2bf(v);
    }
    if (k >= 1 && k < 64) WfT[(size_t)n * KF + 256 + k] = 0;
}

// per-column fused scale/shift for GEMM epilogues (indices 1..4 used)
__global__ void k_affine(const float* __restrict__ enc_b,
                         const float* __restrict__ cb0, const float* __restrict__ bg0, const float* __restrict__ bb0,
                         const float* __restrict__ cb1, const float* __restrict__ bg1, const float* __restrict__ bb1,
                         float* __restrict__ scale, float* __restrict__ shift) {
    int c = threadIdx.x; // 512
    const float inv = 0.9999950000374997f; // 1/sqrt(1+1e-5)
    scale[c] = 1.f; shift[c] = enc_b[c];
    for (int l = 0; l < 2; l++) {
        float s0 = bg0[l * HID + c] * inv;
        scale[(1 + 2 * l) * HID + c] = s0;
        shift[(1 + 2 * l) * HID + c] = cb0[l * HID + c] * s0 + bb0[l * HID + c];
        float s1 = bg1[l * HID + c] * inv;
        scale[(2 + 2 * l) * HID + c] = s1;
        shift[(2 + 2 * l) * HID + c] = cb1[l * HID + c] * s1 + bb1[l * HID + c];
    }
}

// ---------------- CSR build ----------------

__global__ void k_hist(const int* __restrict__ dst, int* __restrict__ indeg, int n) {
    int i = blockIdx.x * blockDim.x + threadIdx.x;
    if (i < n) atomicAdd(&indeg[dst[i]], 1);
}

__global__ void k_scan1(const int* __restrict__ indeg, int* __restrict__ local,
                        int* __restrict__ blocksum, int n) {
    __shared__ int s[256];
    int t = threadIdx.x;
    int i = blockIdx.x * 256 + t;
    int v = (i < n) ? indeg[i] : 0;
    s[t] = v;
    __syncthreads();
    for (int d = 1; d < 256; d <<= 1) {
        int u = (t >= d) ? s[t - d] : 0;
        __syncthreads();
        s[t] += u;
        __syncthreads();
    }
    if (i < n) local[i] = s[t] - v;
    if (t == 255) blocksum[blockIdx.x] = s[255];
}

__global__ void k_scan2(int* __restrict__ blocksum, int nb) {
    __shared__ int s[256];
    int t = threadIdx.x;
    int v = (t < nb) ? blocksum[t] : 0;
    s[t] = v;
    __syncthreads();
    for (int d = 1; d < 256; d <<= 1) {
        int u = (t >= d) ? s[t - d] : 0;
        __syncthreads();
        s[t] += u;
        __syncthreads();
    }
    if (t < nb) blocksum[t] = s[t] - v;
}

__global__ void k_scan3(const int* __restrict__ local, const int* __restrict__ blocksum,
                        const int* __restrict__ indeg, int* __restrict__ off,
                        int* __restrict__ cursor, int n) {
    int i = blockIdx.x * 256 + threadIdx.x;
    if (i < n) {
        int o = local[i] + blocksum[blockIdx.x];
        off[i] = o;
        cursor[i] = o;
        if (i == n - 1) off[n] = o + indeg[i];
    }
}

__global__ void k_fill(const int* __restrict__ src, const int* __restrict__ dst,
                       int* __restrict__ cursor, int* __restrict__ csr, int n) {
    int i = blockIdx.x * blockDim.x + threadIdx.x;
    if (i < n) {
        int p = atomicAdd(&cursor[dst[i]], 1);
        csr[p] = src[i];
    }
}

// ---------------- layer-0 aggregation on RAW 256-dim features + deg column ----------------
// z[i][0:256] = x[i] + sum_{nbr} x[nbr]; z[i][256] = 1+indeg; z[i][257:320] = 0

__global__ void k_aggregate0(const unsigned short* __restrict__ x, const int* __restrict__ off,
                             const int* __restrict__ csr, unsigned short* __restrict__ z) {
    int wid = (int)((blockIdx.x * blockDim.x + threadIdx.x) >> 6);
    if (wid >= NN) return;
    int lane = threadIdx.x & 63;
    const uint2* xr = (const uint2*)x; // row = 64 uint2 (256 bf16)
    uint2 v = xr[(size_t)wid * 64 + lane];
    float acc[4];
    {
        unsigned short* p = (unsigned short*)&v;
        for (int i = 0; i < 4; i++) acc[i] = bf2f(p[i]);
    }
    int e0 = off[wid], e1 = off[wid + 1];
    int e = e0;
    for (; e + 3 < e1; e += 4) {
        int u0 = csr[e], u1 = csr[e + 1], u2 = csr[e + 2], u3 = csr[e + 3];
        uint2 v0 = xr[(size_t)u0 * 64 + lane];
        uint2 v1 = xr[(size_t)u1 * 64 + lane];
        uint2 v2 = xr[(size_t)u2 * 64 + lane];
        uint2 v3 = xr[(size_t)u3 * 64 + lane];
        unsigned short* p0 = (unsigned short*)&v0;
        unsigned short* p1 = (unsigned short*)&v1;
        unsigned short* p2 = (unsigned short*)&v2;
        unsigned short* p3 = (unsigned short*)&v3;
#pragma unroll
        for (int i = 0; i < 4; i++)
            acc[i] += (bf2f(p0[i]) + bf2f(p1[i])) + (bf2f(p2[i]) + bf2f(p3[i]));
    }
    for (; e < e1; e++) {
        int u = csr[e];
        uint2 vu = xr[(size_t)u * 64 + lane];
        unsigned short* p = (unsigned short*)&vu;
#pragma unroll
        for (int i = 0; i < 4; i++) acc[i] += bf2f(p[i]);
    }
    uint2 o;
    unsigned short* po = (unsigned short*)&o;
    for (int i = 0; i < 4; i++) po[i] = f2bf(acc[i]);
    uint2* zr = (uint2*)z; // row = 80 uint2 (320 bf16)
    zr[(size_t)wid * 80 + lane] = o;
    if (lane < 16) {  // cols 256..319
        uint2 ex; ex.x = 0; ex.y = 0;
        if (lane == 0) ex.x = (unsigned)f2bf((float)(1 + e1 - e0)); // deg col 256
        zr[(size_t)wid * 80 + 64 + lane] = ex;
    }
}

// ---------------- layer-1 aggregation: 512-dim ----------------

__global__ void k_aggregate(const unsigned short* __restrict__ x, const int* __restrict__ off,
                            const int* __restrict__ csr, unsigned short* __restrict__ h) {
    int wid = (int)((blockIdx.x * blockDim.x + threadIdx.x) >> 6);
    if (wid >= NN) return;
    int lane = threadIdx.x & 63;
    const uint4* xr = (const uint4*)x; // row = 64 uint4
    uint4 v = xr[(size_t)wid * 64 + lane];
    float acc[8];
    {
        unsigned short* p = (unsigned short*)&v;
        for (int i = 0; i < 8; i++) acc[i] = bf2f(p[i]);
    }
    int e0 = off[wid], e1 = off[wid + 1];
    int e = e0;
    for (; e + 3 < e1; e += 4) {
        int u0 = csr[e], u1 = csr[e + 1], u2 = csr[e + 2], u3 = csr[e + 3];
        uint4 v0 = xr[(size_t)u0 * 64 + lane];
        uint4 v1 = xr[(size_t)u1 * 64 + lane];
        uint4 v2 = xr[(size_t)u2 * 64 + lane];
        uint4 v3 = xr[(size_t)u3 * 64 + lane];
        unsigned short* p0 = (unsigned short*)&v0;
        unsigned short* p1 = (unsigned short*)&v1;
        unsigned short* p2 = (unsigned short*)&v2;
        unsigned short* p3 = (unsigned short*)&v3;
#pragma unroll
        for (int i = 0; i < 8; i++)
            acc[i] += (bf2f(p0[i]) + bf2f(p1[i])) + (bf2f(p2[i]) + bf2f(p3[i]));
    }
    for (; e < e1; e++) {
        int u = csr[e];
        uint4 vu = xr[(size_t)u * 64 + lane];
        unsigned short* p = (unsigned short*)&vu;
#pragma unroll
        for (int i = 0; i < 8; i++) acc[i] += bf2f(p[i]);
    }
    uint4 o;
    unsigned short* po = (unsigned short*)&o;
    for (int i = 0; i < 8; i++) po[i] = f2bf(acc[i]);
    ((uint4*)h)[(size_t)wid * 64 + lane] = o;
}

// ---------------- bf16 MFMA GEMM (R9-verified persistent counted-vmcnt pipeline) ----------------

template <int RELU, int NSTEPS>
__global__ __launch_bounds__(256, 2) void k_gemm(const unsigned short* __restrict__ A,
                                                 const unsigned short* __restrict__ WT,
                                                 const float* __restrict__ scale,
                                                 const float* __restrict__ shift,
                                                 unsigned short* __restrict__ out) {
    constexpr int K = NSTEPS * 64;
    __shared__ char lds[69632]; // [0,64K) dbuf, [64K..) scale/shift
    const int tid = threadIdx.x, w = tid >> 6, lane = tid & 63;
    const int wr = w >> 1, wc = w & 1;
    const int lr = lane & 15, lh = lane >> 4;

    {
        float2 s2 = *(const float2*)(scale + tid * 2);
        float2 h2 = *(const float2*)(shift + tid * 2);
        *(float2*)(lds + 65536 + tid * 8) = s2;
        *(float2*)(lds + 67584 + tid * 8) = h2;
    }
    __syncthreads();

    const int b = blockIdx.x;
    const int xcd = b & 7, slot = b >> 3;
    const int xs = (xcd < 4) ? xcd * 196 : 784 + (xcd - 4) * 195;
    const int xcnt = (xcd < 4) ? 196 : 195;
    const int ntiles = (xcnt - slot + 63) >> 6; // 3 or 4
    int t = xs + slot;

    int ldsoff[4], roff[4];
#pragma unroll
    for (int ci = 0; ci < 4; ci++) {
        int cc = w * 4 + ci;
        ldsoff[ci] = cc * 1024;
        roff[ci] = ((cc >> 1) * 16 + lr) * K + (cc & 1) * 32 + lh * 8;
    }

    const unsigned short* gA[4];
    const unsigned short* gB[4];
    {
        int tile_m = (t >> 2) * 128, n0 = (t & 3) * 128;
#pragma unroll
        for (int ci = 0; ci < 4; ci++) {
            gA[ci] = A + (size_t)tile_m * K + roff[ci];
            gB[ci] = WT + (size_t)n0 * K + roff[ci];
        }
    }

#pragma unroll
    for (int ci = 0; ci < 4; ci++) { async16(gA[ci], lds + ldsoff[ci]); async16(gB[ci], lds + 16384 + ldsoff[ci]); }
#pragma unroll
    for (int ci = 0; ci < 4; ci++) { async16(gA[ci] + 64, lds + 32768 + ldsoff[ci]); async16(gB[ci] + 64, lds + 32768 + 16384 + ldsoff[ci]); }

    for (int i = 0; i < ntiles; i++) {
        const bool last = (i == ntiles - 1);
        const unsigned short* nA[4];
        const unsigned short* nB[4];
        {
            int tn = last ? t : t + 64;
            int tile_m = (tn >> 2) * 128, n0 = (tn & 3) * 128;
#pragma unroll
            for (int ci = 0; ci < 4; ci++) {
                nA[ci] = A + (size_t)tile_m * K + roff[ci];
                nB[ci] = WT + (size_t)n0 * K + roff[ci];
            }
        }

        f32x4 acc[4][4];
#pragma unroll
        for (int x = 0; x < 4; x++)
#pragma unroll
            for (int y = 0; y < 4; y++) acc[x][y] = f32x4{0.f, 0.f, 0.f, 0.f};

#pragma unroll
        for (int ks = 0; ks < NSTEPS; ks++) {
            const int cur = (ks & 1) << 15;
            if (i > 0 && ks < 2)                 asm volatile("s_waitcnt vmcnt(24)" ::: "memory");
            else if (last && ks == NSTEPS - 1)   asm volatile("s_waitcnt vmcnt(0)" ::: "memory");
            else                                 asm volatile("s_waitcnt vmcnt(8)" ::: "memory");
            __builtin_amdgcn_s_barrier();
            __builtin_amdgcn_sched_barrier(0);
#pragma unroll
            for (int kf = 0; kf < 2; kf++) {
                bf16x8 a[4], bb[4];
#pragma unroll
                for (int mf = 0; mf < 4; mf++)
                    a[mf] = *(const bf16x8*)(lds + cur + ((wr * 4 + mf) * 2 + kf) * 1024 + lane * 16);
#pragma unroll
                for (int nf = 0; nf < 4; nf++)
                    bb[nf] = *(const bf16x8*)(lds + cur + 16384 + ((wc * 4 + nf) * 2 + kf) * 1024 + lane * 16);
#pragma unroll
                for (int mf = 0; mf < 4; mf++)
#pragma unroll
                    for (int nf = 0; nf < 4; nf++)
                        acc[mf][nf] = __builtin_amdgcn_mfma_f32_16x16x32_bf16(bb[nf], a[mf], acc[mf][nf], 0, 0, 0);
            }
            __builtin_amdgcn_sched_barrier(0);
            __builtin_amdgcn_s_barrier();
            if (ks + 2 < NSTEPS) {
                int ko = (ks + 2) << 6;
#pragma unroll
                for (int ci = 0; ci < 4; ci++) {
                    async16(gA[ci] + ko, lds + cur + ldsoff[ci]);
                    async16(gB[ci] + ko, lds + cur + 16384 + ldsoff[ci]);
                }
            } else if (!last) {
                int ko = (ks + 2 - NSTEPS) << 6;
#pragma unroll
                for (int ci = 0; ci < 4; ci++) {
                    async16(nA[ci] + ko, lds + cur + ldsoff[ci]);
                    async16(nB[ci] + ko, lds + cur + 16384 + ldsoff[ci]);
                }
            }
        }

        {
            int tile_m = (t >> 2) * 128, n0 = (t & 3) * 128;
#pragma unroll
            for (int nf = 0; nf < 4; nf++) {
                int col = n0 + wc * 64 + nf * 16 + lh * 4;
                f32x4 sc = *(const f32x4*)(lds + 65536 + ((wc * 64 + nf * 16 + lh * 4) << 2) + (n0 << 2));
                f32x4 sh = *(const f32x4*)(lds + 67584 + ((wc * 64 + nf * 16 + lh * 4) << 2) + (n0 << 2));
#pragma unroll
                for (int mf = 0; mf < 4; mf++) {
                    int row = tile_m + wr * 64 + mf * 16 + lr;
                    float y0 = acc[mf][nf][0] * sc[0] + sh[0];
                    float y1 = acc[mf][nf][1] * sc[1] + sh[1];
                    float y2 = acc[mf][nf][2] * sc[2] + sh[2];
                    float y3 = acc[mf][nf][3] * sc[3] + sh[3];
                    if (RELU) {
                        y0 = fmaxf(y0, 0.f); y1 = fmaxf(y1, 0.f);
                        y2 = fmaxf(y2, 0.f); y3 = fmaxf(y3, 0.f);
                    }
                    u32x2 pd;
                    pd[0] = (unsigned)f2bf(y0) | ((unsigned)f2bf(y1) << 16);
                    pd[1] = (unsigned)f2bf(y2) | ((unsigned)f2bf(y3) << 16);
                    unsigned long long ap = (unsigned long long)(out + (size_t)row * HID + col);
                    asm volatile("global_store_dwordx2 %0, %1, off" :: "v"(ap), "v"(pd) : "memory");
                }
            }
        }

        if (!last) {
#pragma unroll
            for (int ci = 0; ci < 4; ci++) { gA[ci] = nA[ci]; gB[ci] = nB[ci]; }
            t += 64;
        }
    }
}

// ---------------- pooling + folded tail ----------------

__global__ void k_bounds(const int* __restrict__ batch, int* __restrict__ bounds) {
    int t = threadIdx.x;
    if (t <= NG) {
        int lo = 0, hi = NN;
        while (lo < hi) { int mid = (lo + hi) >> 1; if (batch[mid] < t) lo = mid + 1; else hi = mid; }
        bounds[t] = lo;
    }
}

__global__ void k_pool(const unsigned short* __restrict__ x, const int* __restrict__ bounds,
                       float* __restrict__ pooled) {
    int g = blockIdx.x, s = blockIdx.y, t = threadIdx.x; // 512 thr
    int b0 = bounds[g], b1 = bounds[g + 1];
    int len = b1 - b0;
    int r0 = b0 + (int)((long long)len * s / 8);
    int r1 = b0 + (int)((long long)len * (s + 1) / 8);
    float acc = 0.f;
    for (int r = r0; r < r1; r++) acc += bf2f(x[(size_t)r * HID + t]);
    if (r1 > r0) atomicAdd(&pooled[g * HID + t], acc);
}

// mean(h1) @ W1 (f32) * s + sh  -> per-graph pooled x_final (exact fold of last conv GEMM)
__global__ void k_tailgemm(const float* __restrict__ pooledSum, const int* __restrict__ bounds,
                           const float* __restrict__ W1, const float* __restrict__ scale,
                           const float* __restrict__ shift, float* __restrict__ xfp) {
    int g = blockIdx.x, t = threadIdx.x; // 512
    __shared__ float row[HID];
    int cnt = bounds[g + 1] - bounds[g];
    float invc = 1.f / fmaxf((float)cnt, 1.f);
    row[t] = pooledSum[g * HID + t] * invc;
    __syncthreads();
    float acc = 0.f;
    for (int k = 0; k < HID; k++) acc += row[k] * W1[(size_t)k * HID + t];
    xfp[g * HID + t] = acc * scale[t] + shift[t];
}

__global__ void k_head1(const float* __restrict__ xfp, const float* __restrict__ lin_w,
                        const float* __restrict__ lin_b, float* __restrict__ gout) {
    int g = blockIdx.x, t = threadIdx.x; // 512
    __shared__ float row[HID];
    row[t] = xfp[g * HID + t];
    __syncthreads();
    float acc = lin_b[t];
    for (int k = 0; k < HID; k++) acc += row[k] * lin_w[(size_t)k * HID + t];
    gout[g * HID + t] = 0.5f * acc * (1.f + erff(acc * 0.7071067811865475f));
}

__global__ void k_head2(const float* __restrict__ gbuf, const float* __restrict__ clf_w,
                        const float* __restrict__ clf_b, float* __restrict__ out) {
    int g = blockIdx.x, t = threadIdx.x; // 128
    __shared__ float row[HID];
    for (int k = t; k < HID; k += 128) row[k] = gbuf[g * HID + k];
    __syncthreads();
    float acc = clf_b[t];
    for (int k = 0; k < HID; k++) acc += row[k] * clf_w[(size_t)k * COUT + t];
    out[g * COUT + t] = acc;
}

// ---------------- launch ----------------

extern "C" void kernel_launch(void* const* d_in, const int* in_sizes, int n_in,
                              void* d_out, int out_size, void* d_ws, size_t ws_size,
                              hipStream_t stream) {
    const float* x_f32   = (const float*)d_in[0];
    const int*   ei      = (const int*)d_in[1];
    const int*   batch   = (const int*)d_in[2];
    const float* enc_w   = (const float*)d_in[3];
    const float* enc_b   = (const float*)d_in[4];
    const float* conv_w0 = (const float*)d_in[5];
    const float* conv_b0 = (const float*)d_in[6];
    const float* bn0_g   = (const float*)d_in[7];
    const float* bn0_b   = (const float*)d_in[8];
    const float* conv_w1 = (const float*)d_in[9];
    const float* conv_b1 = (const float*)d_in[10];
    const float* bn1_g   = (const float*)d_in[11];
    const float* bn1_b   = (const float*)d_in[12];
    const float* lin_w   = (const float*)d_in[13];
    const float* lin_b   = (const float*)d_in[14];
    const float* clf_w   = (const float*)d_in[15];
    const float* clf_b   = (const float*)d_in[16];
    const int* srcp = ei;
    const int* dstp = ei + NE;

    char* ws = (char*)d_ws;
    size_t o = 0;
    auto alloc = [&](size_t b) { size_t r = o; o += (b + 255) & ~(size_t)255; return r; };
    unsigned short* buf0 = (unsigned short*)(ws + alloc((size_t)M_PAD * HID * 2));
    unsigned short* buf1 = (unsigned short*)(ws + alloc((size_t)M_PAD * HID * 2));
    unsigned short* buf2 = (unsigned short*)(ws + alloc((size_t)M_PAD * HID * 2));
    unsigned short* xbf  = buf0;  // alias: raw bf16 feats [NN][256]; dead after k_aggregate0
    unsigned short* zbuf = buf2;  // alias: agg0 output [M_PAD][320]; dead after l0 GEMM
    unsigned short* WfT  = (unsigned short*)(ws + alloc((size_t)HID * KF * 2));
    unsigned short* c0T  = (unsigned short*)(ws + alloc((size_t)HID * HID * 2)); // conv_w0[1]^T
    unsigned short* c1T  = (unsigned short*)(ws + alloc((size_t)HID * HID * 2)); // conv_w1[0]^T
    float* aff_scale = (float*)(ws + alloc(5 * HID * 4));
    float* aff_shift = (float*)(ws + alloc(5 * HID * 4));
    int* indeg  = (int*)(ws + alloc((size_t)NN * 4));
    int* off    = (int*)(ws + alloc((size_t)(NN + 1) * 4));
    int* cursor = (int*)(ws + alloc((size_t)NN * 4));
    int* csr    = (int*)(ws + alloc((size_t)NE * 4));
    int* scan_local = (int*)(ws + alloc((size_t)NN * 4));
    int* scan_bsum  = (int*)(ws + alloc((size_t)256 * 4));
    int* bounds = (int*)(ws + alloc((size_t)(NG + 1) * 4));
    float* pooledSum = (float*)(ws + alloc((size_t)NG * HID * 4));
    float* xfp       = (float*)(ws + alloc((size_t)NG * HID * 4));
    float* gbuf      = (float*)(ws + alloc((size_t)NG * HID * 4));
    (void)ws_size; (void)n_in; (void)in_sizes; (void)out_size;

    hipMemsetAsync(indeg, 0, (size_t)NN * 4, stream);
    hipMemsetAsync(pooledSum, 0, (size_t)NG * HID * 4, stream);

    // weight prep
    k_f32_to_bf16<<<(NN * CIN / 4 + 255) / 256, 256, 0, stream>>>(x_f32, xbf, NN * CIN / 4);
    k_fuse_w0<<<HID, 256, 0, stream>>>(enc_w, enc_b, conv_w0, WfT);
    k_transpose_cvt<<<dim3(16, 16), 256, 0, stream>>>(conv_w0 + HID * HID, c0T, HID, HID);
    k_transpose_cvt<<<dim3(16, 16), 256, 0, stream>>>(conv_w1, c1T, HID, HID);
    k_affine<<<1, 512, 0, stream>>>(enc_b, conv_b0, bn0_g, bn0_b, conv_b1, bn1_g, bn1_b,
                                    aff_scale, aff_shift);

    // CSR (hierarchical scan)
    k_hist<<<(NE + 255) / 256, 256, 0, stream>>>(dstp, indeg, NE);
    k_scan1<<<SCAN_NB, 256, 0, stream>>>(indeg, scan_local, scan_bsum, NN);
    k_scan2<<<1, 256, 0, stream>>>(scan_bsum, SCAN_NB);
    k_scan3<<<SCAN_NB, 256, 0, stream>>>(scan_local, scan_bsum, indeg, off, cursor, NN);
    k_fill<<<(NE + 255) / 256, 256, 0, stream>>>(srcp, dstp, cursor, csr, NE);
    k_bounds<<<1, 128, 0, stream>>>(batch, bounds);

    // layer 0 (folded): agg raw 256-dim feats (+deg col) -> single K=320 GEMM w/ fused weight
    k_aggregate0<<<(NN * 64) / 256, 256, 0, stream>>>(xbf, off, csr, zbuf);
    k_gemm<1, KF / 64><<<GEMM_BLOCKS, 256, 0, stream>>>(zbuf, WfT,
                                                        aff_scale + 1 * HID, aff_shift + 1 * HID, buf0);
    k_gemm<1, HID / 64><<<GEMM_BLOCKS, 256, 0, stream>>>(buf0, c1T,
                                                         aff_scale + 2 * HID, aff_shift + 2 * HID, buf2);

    // layer 1: agg -> GEMM0 (bn0[1]+relu); final GEMM folded into tail
    k_aggregate<<<(NN * 64) / 256, 256, 0, stream>>>(buf2, off, csr, buf1);
    k_gemm<1, HID / 64><<<GEMM_BLOCKS, 256, 0, stream>>>(buf1, c0T,
                                                         aff_scale + 3 * HID, aff_shift + 3 * HID, buf2);

    // tail: pool h1, tiny fp32 GEMM w/ conv_w1[1] + bn1[1] affine, then heads
    k_pool<<<dim3(NG, 8), 512, 0, stream>>>(buf2, bounds, pooledSum);
    k_tailgemm<<<NG, 512, 0, stream>>>(pooledSum, bounds, conv_w1 + HID * HID,
                                       aff_scale + 4 * HID, aff_shift + 4 * HID, xfp);
    k_head1<<<NG, 512, 0, stream>>>(xfp, lin_w, lin_b, gbuf);
    k_head2<<<NG, 128, 0, stream>>>(gbuf, clf_w, clf_b, (float*)d_out);
}